// Round 1
// 109.428 us; speedup vs baseline: 1.0283x; 1.0283x over previous
//
#include <hip/hip_runtime.h>

#define EPSF  (1e-7f)
#define LN2F  (0.69314718055994530942f)

#if __has_builtin(__builtin_amdgcn_logf)
#define LOG2(x) __builtin_amdgcn_logf(x)
#else
#define LOG2(x) __log2f(x)
#endif

// Single-instruction full-wave shift-up-by-1: DPP wave_shr:1 (ctrl 0x138).
// CDNA keeps the gfx9 wave-level DPP shifts (only RDNA removed them).
// bound_ctrl=1 => lane 0 receives a DEFINED 0.0 — relied upon below:
//   a2 = fma(sae,fsc,c0) gives exactly c0=a0 at lane 0 (fma(0,x,c)=c),
//   a3 = sao*fsc_sk gives 0 at lane 0 (both operands 0).
// Bit-identical to the previous row_shr:1+bcast15+cndmask for lanes >= 1.
__device__ __forceinline__ float wshr1_f(float x) {
    return __int_as_float(
        __builtin_amdgcn_update_dpp(0, __float_as_int(x), 0x138, 0xF, 0xF, true));
}
__device__ __forceinline__ int wshr1_i(int x) {
    return __builtin_amdgcn_update_dpp(0, x, 0x138, 0xF, 0xF, true);
}

// Raw workgroup barrier WITHOUT the compiler's vmcnt(0) drain. Residency is
// guaranteed by the producer's own fine-grained s_waitcnt before the barrier.
__device__ __forceinline__ void wg_barrier() {
    asm volatile("" ::: "memory");
    __builtin_amdgcn_s_barrier();
    asm volatile("" ::: "memory");
}

// s_waitcnt immediates (gfx9 encoding: vmcnt[3:0]@0,[5:4]@14; exp@4; lgkm@8)
#define WAITCNT_VM16_ONLY  0x4F70   // vmcnt(16), lgkm/exp no-wait
#define WAITCNT_LGKM0_ONLY 0xC07F   // lgkmcnt(0), vm/exp no-wait

// 2 waves per block, one block per batch element. T=512, C=128, L=64.
// Wave 1 (producer): (a) global->LDS DMA of 16-row phases into a 4-slot raw
//   ring, 3 phases ahead, vmcnt(16) pacing; (b) label-gather: divergent
//   ds_read of raw[j][l_i] + uniform blank raw[j][127], +EPS, packed as
//   float4 (two t-steps) into a 2-slot compact ring (b128 both sides).
// Wave 0 (consumer): pure LINEAR-domain CTC chain (per-lane power-of-2
//   scaling, renorm every 4 steps — exact). Lane i owns states s=2i+1
//   (label) and s=2i+2 (blank); s=0 is the lane-uniform scalar a0.
//   This revision: single-DPP wave_shr:1 shifts, select-free inner step
//   (fma with lane0-masked addend, skip-masked fsc), straight-line phase
//   body when the phase is fully inside Tin. All bit-exact vs previous.
__global__ __launch_bounds__(128, 1)
void ctc_fwd_kernel(const float* __restrict__ y_pred,
                    const int*   __restrict__ labels,
                    const int*   __restrict__ input_length,
                    const int*   __restrict__ label_length,
                    float*       __restrict__ out,
                    int T, int C, int L)
{
    const int b    = blockIdx.x;
    const int wave = threadIdx.x >> 6;
    const int lane = threadIdx.x & 63;
    const int Tin  = input_length[b];
    const int ll   = label_length[b];
    const int NP   = T / 16;                   // 32 phases

    __shared__ float  raw[4][16][128];         // 32 KB raw ring
    __shared__ float4 cmp[2][8][64];           // 16 KB compact ring
                                               // {yl(2j), yb(2j), yl(2j+1), yb(2j+1)}

    const int l = labels[(size_t)b * L + lane];     // 0..C-2, never blank

    if (wave == 1) {
        // ---------------- producer ----------------
        const float* g0 = y_pred + (size_t)b * T * C;
        auto dma = [&](int ph) {
            int slot = ph & 3;
            int phc  = (ph < NP) ? ph : (NP - 1);       // tail: dummy reload
            const float* g = g0 + (size_t)phc * 16 * 128;
            float* lp = &raw[slot][0][0];
            #pragma unroll
            for (int c = 0; c < 8; ++c) {               // 8 x 1KB chunks/phase
                __builtin_amdgcn_global_load_lds(
                    (const __attribute__((address_space(1))) void*)(g + c * 256 + lane * 4),
                    (__attribute__((address_space(3))) void*)(lp + c * 256),
                    16, 0, 0);                          // 16B/lane x 64 = 1KB
            }
        };
        auto gth = [&](int ph) {                        // raw[ph] -> cmp[ph&1]
            int slot = ph & 3, par = ph & 1;
            #pragma unroll
            for (int jj = 0; jj < 8; ++jj) {
                float v0 = raw[slot][2*jj  ][l];        // divergent (producer's slack)
                float b0 = raw[slot][2*jj  ][127];      // uniform -> broadcast
                float v1 = raw[slot][2*jj+1][l];
                float b1 = raw[slot][2*jj+1][127];
                cmp[par][jj][lane] = make_float4(v0 + EPSF, b0 + EPSF,
                                                 v1 + EPSF, b1 + EPSF);
            }
        };
        dma(0); dma(1); dma(2);
        __builtin_amdgcn_s_waitcnt(WAITCNT_VM16_ONLY);  // raw0 resident
        gth(0);
        __builtin_amdgcn_s_waitcnt(WAITCNT_LGKM0_ONLY); // cmp0 visible
        wg_barrier();
        for (int p = 0; p < NP; ++p) {
            dma(p + 3);                                 // 24 outstanding
            __builtin_amdgcn_s_waitcnt(WAITCNT_VM16_ONLY);  // raw[p+1] resident
            gth(p + 1);                                 // (dummy at tail)
            __builtin_amdgcn_s_waitcnt(WAITCNT_LGKM0_ONLY);
            wg_barrier();                               // cmp[p+1] ready
        }
    } else {
        // ---------------- consumer ----------------
        const int  lprev = __shfl_up(l, 1);             // one-time DS op
        const bool skip  = (lane >= 1) && (l != lprev);
        const bool lane0 = (lane == 0);

        float a0 = 0.0f, ao = 0.0f, ae = 0.0f;
        int   esum = 0;                          // biased-exponent tally
        float fsc    = 1.0f;                     // 2^(esum_prev - esum_self)
        float fsc_sk = skip ? 1.0f : 0.0f;       // skip-masked fsc (per renorm)

        float ylv[16], ybv[16];

        // One t-step. Recurrence cycle: wave_shr(1 op) -> mul -> add -> add -> mul.
        // c0 (lane0-masked a0) and fsc/fsc_sk terms are off the critical path.
        auto step = [&](int j) {
            float sae = wshr1_f(ae);             // alpha[2i]   (lane0 -> 0)
            float sao = wshr1_f(ao);             // alpha[2i-1] (lane0 -> 0)
            float c0  = lane0 ? a0 : 0.0f;
            float a2  = fmaf(sae, fsc, c0);      // == lane0 ? a0 : sae*fsc (bit-exact)
            float a3  = sao * fsc_sk;            // == skip  ? sao*fsc : 0  (bit-exact)
            float nao = (ao + a2 + a3) * ylv[j]; // s=2i+1
            float nae = (ae + ao) * ybv[j];      // s=2i+2
            a0 *= ybv[j];                        // s=0
            ao = nao; ae = nae;
        };
        auto renorm = [&]() {                    // every 4 steps — exact 2^k scaling
            float lm    = fmaxf(ae, ao);
            float basis = (lm > 0.0f) ? lm : a0; // a0-anchor if lane dead
            int   e  = (__float_as_int(basis) >> 23) & 0xFF;
            float sc = __int_as_float((254 - e) << 23);  // 2^(127-e)
            ae *= sc; ao *= sc; a0 *= sc;
            esum += e;                           // biased; constant folded at end
            int en = wshr1_i(esum);              // lane0 -> 0 (fsc unused there)
            int de = en - esum;
            de = de < -127 ? -127 : (de > 127 ? 127 : de);
            fsc    = __int_as_float((127 + de) << 23);   // 2^de
            fsc_sk = skip ? fsc : 0.0f;
        };

        wg_barrier();                            // cmp0 ready
        for (int p = 0; p < NP; ++p) {
            const int par = p & 1;
            #pragma unroll
            for (int jj = 0; jj < 8; ++jj) {     // 8 conflict-free ds_read_b128
                float4 v = cmp[par][jj][lane];
                ylv[2*jj  ] = v.x; ybv[2*jj  ] = v.y;
                ylv[2*jj+1] = v.z; ybv[2*jj+1] = v.w;
            }
            const int t0 = p << 4;
            if (p != 0 && t0 + 16 <= Tin) {
                // Fast path: whole phase inside Tin, no t==0 — one straight-line
                // region so the scheduler fills dependency bubbles across steps.
                #pragma unroll
                for (int j = 0; j < 16; ++j) {
                    step(j);
                    if ((j & 3) == 3) renorm();
                }
            } else {
                #pragma unroll
                for (int j = 0; j < 16; ++j) {
                    const int t = t0 + j;
                    if (t < Tin) {               // wave-uniform
                        if (t == 0) {
                            a0 = ybv[0];
                            ao = lane0 ? ylv[0] : 0.0f;
                            ae = 0.0f;
                        } else {
                            step(j);
                        }
                    }
                    if ((j & 3) == 3) renorm();  // runs NP*4 times total (both paths)
                }
            }
            wg_barrier();                        // next phase's cmp ready
        }

        // s_end = 2*ll -> lane (ll-1).ae ; s_end-1 -> lane (ll-1).ao ; ll >= 16
        if (lane == ll - 1) {
            float pfin = ae + ao;                // lane's own scale
            // esum accumulated biased exponents: subtract 127 per renorm (NP*4 of them)
            out[b] = -(LOG2(pfin) + (float)(esum - NP * 4 * 127)) * LN2F;
        }
    }
}

extern "C" void kernel_launch(void* const* d_in, const int* in_sizes, int n_in,
                              void* d_out, int out_size, void* d_ws, size_t ws_size,
                              hipStream_t stream) {
    const float* y_pred       = (const float*)d_in[0];
    const int*   labels       = (const int*)d_in[1];
    const int*   input_length = (const int*)d_in[2];
    const int*   label_length = (const int*)d_in[3];
    float*       out          = (float*)d_out;

    const int B = in_sizes[2];          // 256
    const int L = in_sizes[1] / B;      // 64
    const int T = 512;
    const int C = 128;

    ctc_fwd_kernel<<<B, 128, 0, stream>>>(y_pred, labels, input_length,
                                          label_length, out, T, C, L);
}